// Round 1
// baseline (659.850 us; speedup 1.0000x reference)
//
#include <hip/hip_runtime.h>
#include <math.h>

// Problem constants (shapes fixed by the reference)
// N=50000 nodes, E=800000 edges, D=64, H=2 heads, C=64 per-head, H*C=128

// ---------------------------------------------------------------------------
// CSR build kernels
// ---------------------------------------------------------------------------
__global__ __launch_bounds__(256) void hist_kernel(const int* __restrict__ dst,
                                                   int* __restrict__ counts, int e) {
    int i = blockIdx.x * 256 + threadIdx.x;
    if (i < e) atomicAdd(&counts[dst[i]], 1);
}

__global__ __launch_bounds__(1024) void scan_kernel(const int* __restrict__ counts,
                                                    int* __restrict__ offsets,
                                                    int* __restrict__ cursor,
                                                    int n, int total) {
    __shared__ int sums[1024];
    const int t = threadIdx.x;
    const int chunk = (n + 1023) >> 10;
    const int base = t * chunk;
    int local = 0;
    for (int i = 0; i < chunk; ++i) {
        int idx = base + i;
        if (idx < n) local += counts[idx];
    }
    sums[t] = local;
    __syncthreads();
    // Hillis-Steele inclusive scan over 1024 partial sums
    for (int off = 1; off < 1024; off <<= 1) {
        int val = (t >= off) ? sums[t - off] : 0;
        __syncthreads();
        sums[t] += val;
        __syncthreads();
    }
    int run = sums[t] - local;  // exclusive prefix for this thread's chunk
    for (int i = 0; i < chunk; ++i) {
        int idx = base + i;
        if (idx < n) {
            offsets[idx] = run;
            cursor[idx]  = run;
            run += counts[idx];
        }
    }
    if (t == 0) offsets[n] = total;
}

__global__ __launch_bounds__(256) void scatter_kernel(const int* __restrict__ src,
                                                      const int* __restrict__ dst,
                                                      int* __restrict__ cursor,
                                                      int* __restrict__ ssrc, int e) {
    int i = blockIdx.x * 256 + threadIdx.x;
    if (i < e) {
        int pos = atomicAdd(&cursor[dst[i]], 1);
        ssrc[pos] = src[i];
    }
}

// ---------------------------------------------------------------------------
// Tiled fp32 GEMM: X[rows,64] @ W[64,NCOLS] + B -> O[rows,NCOLS]
// 64-row tile; x tile + full weight panel in LDS; 16x16 thread micro-tiles.
// ---------------------------------------------------------------------------
template <int NCOLS>
__global__ __launch_bounds__(256) void gemm_tile(const float* __restrict__ X, int rows,
                                                 const float* __restrict__ W,
                                                 const float* __restrict__ B,
                                                 float* __restrict__ O) {
    constexpr int CT = NCOLS / 16;  // cols per thread (8 or 4)
    __shared__ float xs[64][65];    // +1 pad: kills stride-64 bank conflict
    __shared__ float wsm[64][NCOLS];
    const int t  = threadIdx.x;
    const int r0 = blockIdx.x * 64;

#pragma unroll
    for (int i = 0; i < 16; ++i) {
        int idx = i * 256 + t;
        int rr = idx >> 6, cc = idx & 63;
        int row = r0 + rr;
        xs[rr][cc] = (row < rows) ? X[(size_t)row * 64 + cc] : 0.f;
    }
    for (int i = t; i < 64 * NCOLS; i += 256) {
        wsm[i / NCOLS][i % NCOLS] = W[i];
    }
    __syncthreads();

    const int tx = t & 15, ty = t >> 4;
    float acc[4][CT];
#pragma unroll
    for (int r = 0; r < 4; ++r)
#pragma unroll
        for (int c = 0; c < CT; ++c) acc[r][c] = 0.f;

#pragma unroll 4
    for (int kk = 0; kk < 64; ++kk) {
        float a[4];
#pragma unroll
        for (int r = 0; r < 4; ++r) a[r] = xs[ty * 4 + r][kk];
        float b[CT];
#pragma unroll
        for (int c = 0; c < CT; ++c) b[c] = wsm[kk][tx * CT + c];
#pragma unroll
        for (int r = 0; r < 4; ++r)
#pragma unroll
            for (int c = 0; c < CT; ++c) acc[r][c] = fmaf(a[r], b[c], acc[r][c]);
    }

#pragma unroll
    for (int r = 0; r < 4; ++r) {
        int row = r0 + ty * 4 + r;
        if (row < rows) {
#pragma unroll
            for (int c = 0; c < CT; ++c)
                O[(size_t)row * NCOLS + tx * CT + c] = acc[r][c] + B[tx * CT + c];
        }
    }
}

// ---------------------------------------------------------------------------
// Attention: one wave per destination node. Lanes 0-31 = head 0, 32-63 = head 1;
// each lane owns 2 channels (float2). Online softmax over incoming edges.
// out += mean_over_heads(softmax(qk/8) @ v)   (out pre-filled with skip)
// ---------------------------------------------------------------------------
__global__ __launch_bounds__(256) void attn_kernel(const float* __restrict__ Q,
                                                   const float* __restrict__ K,
                                                   const float* __restrict__ V,
                                                   const int* __restrict__ offs,
                                                   const int* __restrict__ ssrc,
                                                   float* __restrict__ out, int n) {
    int gid  = blockIdx.x * 256 + threadIdx.x;
    int node = gid >> 6;
    int lane = threadIdx.x & 63;
    if (node >= n) return;

    const float2 qv = *(const float2*)(Q + (size_t)node * 128 + lane * 2);
    const int beg = offs[node], end = offs[node + 1];

    float m = -INFINITY, l = 0.f;
    float2 acc = make_float2(0.f, 0.f);

    for (int i = beg; i < end; ++i) {
        int s = ssrc[i];
        const float2 kv = *(const float2*)(K + (size_t)s * 128 + lane * 2);
        float part = qv.x * kv.x + qv.y * kv.y;
        part += __shfl_xor(part, 1);
        part += __shfl_xor(part, 2);
        part += __shfl_xor(part, 4);
        part += __shfl_xor(part, 8);
        part += __shfl_xor(part, 16);
        float alpha = part * 0.125f;  // / sqrt(C=64)

        float mnew  = fmaxf(m, alpha);
        float scale = __expf(m - mnew);      // m=-inf -> 0
        float p     = __expf(alpha - mnew);

        const float2 vv = *(const float2*)(V + (size_t)s * 128 + lane * 2);
        acc.x = fmaf(p, vv.x, acc.x * scale);
        acc.y = fmaf(p, vv.y, acc.y * scale);
        l     = l * scale + p;
        m     = mnew;
    }

    float inv = 1.f / (l + 1e-16f);
    float rx = acc.x * inv, ry = acc.y * inv;
    float ox = __shfl_xor(rx, 32);
    float oy = __shfl_xor(ry, 32);
    float mx = 0.5f * (rx + ox), my = 0.5f * (ry + oy);

    if (lane < 32) {
        float2* o = (float2*)(out + (size_t)node * 64 + lane * 2);
        float2 cur = *o;
        cur.x += mx;
        cur.y += my;
        *o = cur;
    }
}

// ---------------------------------------------------------------------------
// Host launch
// ---------------------------------------------------------------------------
extern "C" void kernel_launch(void* const* d_in, const int* in_sizes, int n_in,
                              void* d_out, int out_size, void* d_ws, size_t ws_size,
                              hipStream_t stream) {
    const float* x  = (const float*)d_in[0];
    const int*   ei = (const int*)d_in[1];  // [2,E]: row0=src, row1=dst
    const int N = in_sizes[0] / 64;
    const int E = in_sizes[1] / 2;

    const float* w[16];
    for (int i = 0; i < 16; ++i) w[i] = (const float*)d_in[2 + i];

    // workspace layout
    char* base = (char*)d_ws;
    size_t off = 0;
    auto alloc = [&](size_t bytes) {
        void* p = base + off;
        off = (off + bytes + 255) & ~(size_t)255;
        return p;
    };
    float* q    = (float*)alloc((size_t)N * 128 * 4);
    float* kbuf = (float*)alloc((size_t)N * 128 * 4);
    float* v    = (float*)alloc((size_t)N * 128 * 4);
    float* h1   = (float*)alloc((size_t)N * 64 * 4);
    int* counts  = (int*)alloc((size_t)N * 4);
    int* offsets = (int*)alloc((size_t)(N + 1) * 4);
    int* cursor  = (int*)alloc((size_t)N * 4);
    int* ssrc    = (int*)alloc((size_t)E * 4);

    // --- CSR build (graph shared by both layers) ---
    hipMemsetAsync(counts, 0, (size_t)N * 4, stream);
    int eb = (E + 255) / 256;
    hist_kernel<<<eb, 256, 0, stream>>>(ei + E, counts, E);
    scan_kernel<<<1, 1024, 0, stream>>>(counts, offsets, cursor, N, E);
    scatter_kernel<<<eb, 256, 0, stream>>>(ei, ei + E, cursor, ssrc, E);

    const int gb = (N + 63) / 64;
    const int ab = (N * 64 + 255) / 256;

    for (int layer = 0; layer < 2; ++layer) {
        const float* in = layer ? h1 : x;
        float* outp = layer ? (float*)d_out : h1;
        const float* const* W = w + layer * 8;
        gemm_tile<128><<<gb, 256, 0, stream>>>(in, N, W[0], W[1], q);     // Q
        gemm_tile<128><<<gb, 256, 0, stream>>>(in, N, W[2], W[3], kbuf);  // K
        gemm_tile<128><<<gb, 256, 0, stream>>>(in, N, W[4], W[5], v);     // V
        gemm_tile<64><<<gb, 256, 0, stream>>>(in, N, W[6], W[7], outp);   // skip
        attn_kernel<<<ab, 256, 0, stream>>>(q, kbuf, v, offsets, ssrc, outp, N);
    }
}

// Round 2
// 472.386 us; speedup vs baseline: 1.3968x; 1.3968x over previous
//
#include <hip/hip_runtime.h>
#include <hip/hip_fp16.h>
#include <math.h>

// N=50000 nodes, E=800000 edges, D=64, H=2 heads, C=64 per-head, H*C=128

// ---------------------------------------------------------------------------
// CSR build kernels
// ---------------------------------------------------------------------------
__global__ __launch_bounds__(256) void hist_kernel(const int* __restrict__ dst,
                                                   int* __restrict__ counts, int e) {
    int i = blockIdx.x * 256 + threadIdx.x;
    if (i < e) atomicAdd(&counts[dst[i]], 1);
}

__global__ __launch_bounds__(1024) void scan_kernel(const int* __restrict__ counts,
                                                    int* __restrict__ offsets,
                                                    int* __restrict__ cursor,
                                                    int n, int total) {
    __shared__ int sums[1024];
    const int t = threadIdx.x;
    const int chunk = (n + 1023) >> 10;
    const int base = t * chunk;
    int local = 0;
    for (int i = 0; i < chunk; ++i) {
        int idx = base + i;
        if (idx < n) local += counts[idx];
    }
    sums[t] = local;
    __syncthreads();
    for (int off = 1; off < 1024; off <<= 1) {
        int val = (t >= off) ? sums[t - off] : 0;
        __syncthreads();
        sums[t] += val;
        __syncthreads();
    }
    int run = sums[t] - local;  // exclusive prefix
    for (int i = 0; i < chunk; ++i) {
        int idx = base + i;
        if (idx < n) {
            offsets[idx] = run;
            cursor[idx]  = run;
            run += counts[idx];
        }
    }
    if (t == 0) offsets[n] = total;
}

__global__ __launch_bounds__(256) void scatter_kernel(const int* __restrict__ src,
                                                      const int* __restrict__ dst,
                                                      int* __restrict__ cursor,
                                                      int* __restrict__ ssrc, int e) {
    int i = blockIdx.x * 256 + threadIdx.x;
    if (i < e) {
        int pos = atomicAdd(&cursor[dst[i]], 1);
        ssrc[pos] = src[i];
    }
}

// ---------------------------------------------------------------------------
// Fused GEMM: one X tile, four weight panels.
//   Q  = X@Wq+bq  -> fp32 [N,128]
//   K  = X@Wk+bk  -> fp16 [N,128]
//   V  = X@Wv+bv  -> fp16 [N,128]
//   S  = X@Ws+bs  -> fp32 [N,64]  (skip, written into layer output)
// ---------------------------------------------------------------------------
__global__ __launch_bounds__(256) void gemm_fused(
    const float* __restrict__ X, int rows,
    const float* __restrict__ Wq, const float* __restrict__ Bq,
    const float* __restrict__ Wk, const float* __restrict__ Bk,
    const float* __restrict__ Wv, const float* __restrict__ Bv,
    const float* __restrict__ Ws, const float* __restrict__ Bs,
    float* __restrict__ Qo, __half* __restrict__ Ko, __half* __restrict__ Vo,
    float* __restrict__ skipo) {
    __shared__ float xs[64][65];    // +1 pad kills stride-64 conflicts
    __shared__ float wsm[64][128];
    const int t  = threadIdx.x;
    const int r0 = blockIdx.x * 64;

#pragma unroll
    for (int i = 0; i < 16; ++i) {
        int idx = i * 256 + t;
        int rr = idx >> 6, cc = idx & 63;
        int row = r0 + rr;
        xs[rr][cc] = (row < rows) ? X[(size_t)row * 64 + cc] : 0.f;
    }
    const int tx = t & 15, ty = t >> 4;

    // ---- panel Q (fp32 out) ----
    for (int i = t; i < 64 * 128; i += 256) wsm[i >> 7][i & 127] = Wq[i];
    __syncthreads();
    {
        float acc[4][8] = {};
#pragma unroll 4
        for (int kk = 0; kk < 64; ++kk) {
            float a[4];
#pragma unroll
            for (int r = 0; r < 4; ++r) a[r] = xs[ty * 4 + r][kk];
            float b[8];
#pragma unroll
            for (int c = 0; c < 8; ++c) b[c] = wsm[kk][tx * 8 + c];
#pragma unroll
            for (int r = 0; r < 4; ++r)
#pragma unroll
                for (int c = 0; c < 8; ++c) acc[r][c] = fmaf(a[r], b[c], acc[r][c]);
        }
#pragma unroll
        for (int r = 0; r < 4; ++r) {
            int row = r0 + ty * 4 + r;
            if (row < rows)
#pragma unroll
                for (int c = 0; c < 8; ++c)
                    Qo[(size_t)row * 128 + tx * 8 + c] = acc[r][c] + Bq[tx * 8 + c];
        }
    }
    __syncthreads();

    // ---- panel K (fp16 out) ----
    for (int i = t; i < 64 * 128; i += 256) wsm[i >> 7][i & 127] = Wk[i];
    __syncthreads();
    {
        float acc[4][8] = {};
#pragma unroll 4
        for (int kk = 0; kk < 64; ++kk) {
            float a[4];
#pragma unroll
            for (int r = 0; r < 4; ++r) a[r] = xs[ty * 4 + r][kk];
            float b[8];
#pragma unroll
            for (int c = 0; c < 8; ++c) b[c] = wsm[kk][tx * 8 + c];
#pragma unroll
            for (int r = 0; r < 4; ++r)
#pragma unroll
                for (int c = 0; c < 8; ++c) acc[r][c] = fmaf(a[r], b[c], acc[r][c]);
        }
#pragma unroll
        for (int r = 0; r < 4; ++r) {
            int row = r0 + ty * 4 + r;
            if (row < rows)
#pragma unroll
                for (int c = 0; c < 8; ++c)
                    Ko[(size_t)row * 128 + tx * 8 + c] =
                        __float2half_rn(acc[r][c] + Bk[tx * 8 + c]);
        }
    }
    __syncthreads();

    // ---- panel V (fp16 out) ----
    for (int i = t; i < 64 * 128; i += 256) wsm[i >> 7][i & 127] = Wv[i];
    __syncthreads();
    {
        float acc[4][8] = {};
#pragma unroll 4
        for (int kk = 0; kk < 64; ++kk) {
            float a[4];
#pragma unroll
            for (int r = 0; r < 4; ++r) a[r] = xs[ty * 4 + r][kk];
            float b[8];
#pragma unroll
            for (int c = 0; c < 8; ++c) b[c] = wsm[kk][tx * 8 + c];
#pragma unroll
            for (int r = 0; r < 4; ++r)
#pragma unroll
                for (int c = 0; c < 8; ++c) acc[r][c] = fmaf(a[r], b[c], acc[r][c]);
        }
#pragma unroll
        for (int r = 0; r < 4; ++r) {
            int row = r0 + ty * 4 + r;
            if (row < rows)
#pragma unroll
                for (int c = 0; c < 8; ++c)
                    Vo[(size_t)row * 128 + tx * 8 + c] =
                        __float2half_rn(acc[r][c] + Bv[tx * 8 + c]);
        }
    }
    __syncthreads();

    // ---- panel skip (64 cols, fp32 out) ----
    for (int i = t; i < 64 * 64; i += 256) wsm[i >> 6][i & 63] = Ws[i];
    __syncthreads();
    {
        float acc[4][4] = {};
#pragma unroll 4
        for (int kk = 0; kk < 64; ++kk) {
            float a[4];
#pragma unroll
            for (int r = 0; r < 4; ++r) a[r] = xs[ty * 4 + r][kk];
            float b[4];
#pragma unroll
            for (int c = 0; c < 4; ++c) b[c] = wsm[kk][tx * 4 + c];
#pragma unroll
            for (int r = 0; r < 4; ++r)
#pragma unroll
                for (int c = 0; c < 4; ++c) acc[r][c] = fmaf(a[r], b[c], acc[r][c]);
        }
#pragma unroll
        for (int r = 0; r < 4; ++r) {
            int row = r0 + ty * 4 + r;
            if (row < rows)
#pragma unroll
                for (int c = 0; c < 4; ++c)
                    skipo[(size_t)row * 64 + tx * 4 + c] = acc[r][c] + Bs[tx * 4 + c];
        }
    }
}

// ---------------------------------------------------------------------------
// Attention: one wave per dst node; lanes 0-31 head0, 32-63 head1, 2 ch/lane.
// fp16 K/V gathers, 4-edge batched online softmax.
// ---------------------------------------------------------------------------
__global__ __launch_bounds__(256) void attn_kernel(const float* __restrict__ Q,
                                                   const __half* __restrict__ K,
                                                   const __half* __restrict__ V,
                                                   const int* __restrict__ offs,
                                                   const int* __restrict__ ssrc,
                                                   float* __restrict__ out, int n) {
    int gid  = blockIdx.x * 256 + threadIdx.x;
    int node = gid >> 6;
    int lane = threadIdx.x & 63;
    if (node >= n) return;

    const float2 qv = *(const float2*)(Q + (size_t)node * 128 + lane * 2);
    const int beg = offs[node], end = offs[node + 1];

    const __half2* K2 = (const __half2*)K;
    const __half2* V2 = (const __half2*)V;

    float m = -INFINITY, l = 0.f;
    float2 acc = make_float2(0.f, 0.f);

    int i = beg;
    for (; i + 4 <= end; i += 4) {
        int s0 = ssrc[i], s1 = ssrc[i + 1], s2 = ssrc[i + 2], s3 = ssrc[i + 3];
        __half2 hk0 = K2[(size_t)s0 * 64 + lane];
        __half2 hk1 = K2[(size_t)s1 * 64 + lane];
        __half2 hk2 = K2[(size_t)s2 * 64 + lane];
        __half2 hk3 = K2[(size_t)s3 * 64 + lane];
        __half2 hv0 = V2[(size_t)s0 * 64 + lane];
        __half2 hv1 = V2[(size_t)s1 * 64 + lane];
        __half2 hv2 = V2[(size_t)s2 * 64 + lane];
        __half2 hv3 = V2[(size_t)s3 * 64 + lane];

        float d0 = fmaf(qv.x, __half2float(hk0.x), qv.y * __half2float(hk0.y));
        float d1 = fmaf(qv.x, __half2float(hk1.x), qv.y * __half2float(hk1.y));
        float d2 = fmaf(qv.x, __half2float(hk2.x), qv.y * __half2float(hk2.y));
        float d3 = fmaf(qv.x, __half2float(hk3.x), qv.y * __half2float(hk3.y));

        d0 += __shfl_xor(d0, 1);  d1 += __shfl_xor(d1, 1);
        d2 += __shfl_xor(d2, 1);  d3 += __shfl_xor(d3, 1);
        d0 += __shfl_xor(d0, 2);  d1 += __shfl_xor(d1, 2);
        d2 += __shfl_xor(d2, 2);  d3 += __shfl_xor(d3, 2);
        d0 += __shfl_xor(d0, 4);  d1 += __shfl_xor(d1, 4);
        d2 += __shfl_xor(d2, 4);  d3 += __shfl_xor(d3, 4);
        d0 += __shfl_xor(d0, 8);  d1 += __shfl_xor(d1, 8);
        d2 += __shfl_xor(d2, 8);  d3 += __shfl_xor(d3, 8);
        d0 += __shfl_xor(d0, 16); d1 += __shfl_xor(d1, 16);
        d2 += __shfl_xor(d2, 16); d3 += __shfl_xor(d3, 16);

        float a0 = d0 * 0.125f, a1 = d1 * 0.125f, a2 = d2 * 0.125f, a3 = d3 * 0.125f;
        float mx = fmaxf(fmaxf(fmaxf(a0, a1), fmaxf(a2, a3)), m);
        float scale = __expf(m - mx);
        float p0 = __expf(a0 - mx), p1 = __expf(a1 - mx);
        float p2 = __expf(a2 - mx), p3 = __expf(a3 - mx);

        float ax = acc.x * scale, ay = acc.y * scale;
        ax = fmaf(p0, __half2float(hv0.x), ax);
        ay = fmaf(p0, __half2float(hv0.y), ay);
        ax = fmaf(p1, __half2float(hv1.x), ax);
        ay = fmaf(p1, __half2float(hv1.y), ay);
        ax = fmaf(p2, __half2float(hv2.x), ax);
        ay = fmaf(p2, __half2float(hv2.y), ay);
        ax = fmaf(p3, __half2float(hv3.x), ax);
        ay = fmaf(p3, __half2float(hv3.y), ay);
        acc.x = ax; acc.y = ay;
        l = fmaf(l, scale, p0 + p1 + p2 + p3);
        m = mx;
    }
    for (; i < end; ++i) {
        int s = ssrc[i];
        __half2 hk = K2[(size_t)s * 64 + lane];
        __half2 hv = V2[(size_t)s * 64 + lane];
        float d = fmaf(qv.x, __half2float(hk.x), qv.y * __half2float(hk.y));
        d += __shfl_xor(d, 1);
        d += __shfl_xor(d, 2);
        d += __shfl_xor(d, 4);
        d += __shfl_xor(d, 8);
        d += __shfl_xor(d, 16);
        float a = d * 0.125f;
        float mnew  = fmaxf(m, a);
        float scale = __expf(m - mnew);
        float p     = __expf(a - mnew);
        acc.x = fmaf(p, __half2float(hv.x), acc.x * scale);
        acc.y = fmaf(p, __half2float(hv.y), acc.y * scale);
        l = fmaf(l, scale, p);
        m = mnew;
    }

    float inv = 1.f / (l + 1e-16f);
    float rx = acc.x * inv, ry = acc.y * inv;
    float ox = __shfl_xor(rx, 32);
    float oy = __shfl_xor(ry, 32);
    float mx2 = 0.5f * (rx + ox), my2 = 0.5f * (ry + oy);

    if (lane < 32) {
        float2* o = (float2*)(out + (size_t)node * 64 + lane * 2);
        float2 cur = *o;
        cur.x += mx2;
        cur.y += my2;
        *o = cur;
    }
}

// ---------------------------------------------------------------------------
// Host launch
// ---------------------------------------------------------------------------
extern "C" void kernel_launch(void* const* d_in, const int* in_sizes, int n_in,
                              void* d_out, int out_size, void* d_ws, size_t ws_size,
                              hipStream_t stream) {
    const float* x  = (const float*)d_in[0];
    const int*   ei = (const int*)d_in[1];  // [2,E]: row0=src, row1=dst
    const int N = in_sizes[0] / 64;
    const int E = in_sizes[1] / 2;

    const float* w[16];
    for (int i = 0; i < 16; ++i) w[i] = (const float*)d_in[2 + i];

    char* base = (char*)d_ws;
    size_t off = 0;
    auto alloc = [&](size_t bytes) {
        void* p = base + off;
        off = (off + bytes + 255) & ~(size_t)255;
        return p;
    };
    float*  q    = (float*)alloc((size_t)N * 128 * 4);
    __half* kbuf = (__half*)alloc((size_t)N * 128 * 2);
    __half* v    = (__half*)alloc((size_t)N * 128 * 2);
    float*  h1   = (float*)alloc((size_t)N * 64 * 4);
    int* counts  = (int*)alloc((size_t)N * 4);
    int* offsets = (int*)alloc((size_t)(N + 1) * 4);
    int* cursor  = (int*)alloc((size_t)N * 4);
    int* ssrc    = (int*)alloc((size_t)E * 4);

    // --- CSR build (graph shared by both layers) ---
    hipMemsetAsync(counts, 0, (size_t)N * 4, stream);
    int eb = (E + 255) / 256;
    hist_kernel<<<eb, 256, 0, stream>>>(ei + E, counts, E);
    scan_kernel<<<1, 1024, 0, stream>>>(counts, offsets, cursor, N, E);
    scatter_kernel<<<eb, 256, 0, stream>>>(ei, ei + E, cursor, ssrc, E);

    const int gb = (N + 63) / 64;
    const int ab = (N * 64 + 255) / 256;

    for (int layer = 0; layer < 2; ++layer) {
        const float* in = layer ? h1 : x;
        float* outp = layer ? (float*)d_out : h1;
        const float* const* W = w + layer * 8;
        gemm_fused<<<gb, 256, 0, stream>>>(in, N, W[0], W[1], W[2], W[3], W[4], W[5],
                                           W[6], W[7], q, kbuf, v, outp);
        attn_kernel<<<ab, 256, 0, stream>>>(q, kbuf, v, offsets, ssrc, outp, N);
    }
}

// Round 3
// 350.505 us; speedup vs baseline: 1.8826x; 1.3477x over previous
//
#include <hip/hip_runtime.h>
#include <hip/hip_fp16.h>
#include <math.h>

// N=50000 nodes, E=800000 edges, D=64, H=2 heads, C=64 per-head, H*C=128

// ---------------------------------------------------------------------------
// CSR build kernels
// ---------------------------------------------------------------------------
__global__ __launch_bounds__(256) void hist_kernel(const int* __restrict__ dst,
                                                   int* __restrict__ counts, int e) {
    int i = blockIdx.x * 256 + threadIdx.x;
    if (i < e) atomicAdd(&counts[dst[i]], 1);
}

// Phase 1: per-block (256-element segment) reduction of counts -> partials
__global__ __launch_bounds__(256) void partial_kernel(const int* __restrict__ counts,
                                                      int* __restrict__ partials, int n) {
    int idx = blockIdx.x * 256 + threadIdx.x;
    int v = (idx < n) ? counts[idx] : 0;
    // wave reduce (64 lanes)
    for (int off = 1; off < 64; off <<= 1) v += __shfl_xor(v, off);
    __shared__ int ws[4];
    int wid = threadIdx.x >> 6;
    if ((threadIdx.x & 63) == 0) ws[wid] = v;
    __syncthreads();
    if (threadIdx.x == 0)
        partials[blockIdx.x] = ws[0] + ws[1] + ws[2] + ws[3];
}

// Phase 2: single block exclusive-scans partials[nb] -> blockbase[nb]
__global__ __launch_bounds__(256) void scanp_kernel(const int* __restrict__ partials,
                                                    int* __restrict__ blockbase, int nb) {
    __shared__ int s[256];
    int t = threadIdx.x;
    int v = (t < nb) ? partials[t] : 0;
    s[t] = v;
    __syncthreads();
    for (int off = 1; off < 256; off <<= 1) {
        int u = (t >= off) ? s[t - off] : 0;
        __syncthreads();
        s[t] += u;
        __syncthreads();
    }
    if (t < nb) blockbase[t] = s[t] - v;  // exclusive
}

// Phase 3: per-block exclusive scan of its tile + blockbase -> offsets, cursor
__global__ __launch_bounds__(256) void final_kernel(const int* __restrict__ counts,
                                                    const int* __restrict__ blockbase,
                                                    int* __restrict__ offsets,
                                                    int* __restrict__ cursor,
                                                    int n, int total) {
    __shared__ int s[256];
    int t = threadIdx.x;
    int idx = blockIdx.x * 256 + t;
    int v = (idx < n) ? counts[idx] : 0;
    s[t] = v;
    __syncthreads();
    for (int off = 1; off < 256; off <<= 1) {
        int u = (t >= off) ? s[t - off] : 0;
        __syncthreads();
        s[t] += u;
        __syncthreads();
    }
    if (idx < n) {
        int ex = blockbase[blockIdx.x] + s[t] - v;
        offsets[idx] = ex;
        cursor[idx]  = ex;
    }
    if (idx == 0) offsets[n] = total;
}

__global__ __launch_bounds__(256) void scatter_kernel(const int* __restrict__ src,
                                                      const int* __restrict__ dst,
                                                      int* __restrict__ cursor,
                                                      int* __restrict__ ssrc, int e) {
    int i = blockIdx.x * 256 + threadIdx.x;
    if (i < e) {
        int pos = atomicAdd(&cursor[dst[i]], 1);
        ssrc[pos] = src[i];
    }
}

// ---------------------------------------------------------------------------
// Fused GEMM: one X tile, four weight panels.
//   Q  = X@Wq+bq  -> fp32 [N,128]
//   K  = X@Wk+bk  -> fp16 [N,128]
//   V  = X@Wv+bv  -> fp16 [N,128]
//   S  = X@Ws+bs  -> fp32 [N,64]  (skip, written into layer output)
// ---------------------------------------------------------------------------
__global__ __launch_bounds__(256) void gemm_fused(
    const float* __restrict__ X, int rows,
    const float* __restrict__ Wq, const float* __restrict__ Bq,
    const float* __restrict__ Wk, const float* __restrict__ Bk,
    const float* __restrict__ Wv, const float* __restrict__ Bv,
    const float* __restrict__ Ws, const float* __restrict__ Bs,
    float* __restrict__ Qo, __half* __restrict__ Ko, __half* __restrict__ Vo,
    float* __restrict__ skipo) {
    __shared__ float xs[64][65];    // +1 pad kills stride-64 conflicts
    __shared__ float wsm[64][128];
    const int t  = threadIdx.x;
    const int r0 = blockIdx.x * 64;

#pragma unroll
    for (int i = 0; i < 16; ++i) {
        int idx = i * 256 + t;
        int rr = idx >> 6, cc = idx & 63;
        int row = r0 + rr;
        xs[rr][cc] = (row < rows) ? X[(size_t)row * 64 + cc] : 0.f;
    }
    const int tx = t & 15, ty = t >> 4;

    // ---- panel Q (fp32 out) ----
    for (int i = t; i < 64 * 128; i += 256) wsm[i >> 7][i & 127] = Wq[i];
    __syncthreads();
    {
        float acc[4][8] = {};
#pragma unroll 4
        for (int kk = 0; kk < 64; ++kk) {
            float a[4];
#pragma unroll
            for (int r = 0; r < 4; ++r) a[r] = xs[ty * 4 + r][kk];
            float b[8];
#pragma unroll
            for (int c = 0; c < 8; ++c) b[c] = wsm[kk][tx * 8 + c];
#pragma unroll
            for (int r = 0; r < 4; ++r)
#pragma unroll
                for (int c = 0; c < 8; ++c) acc[r][c] = fmaf(a[r], b[c], acc[r][c]);
        }
#pragma unroll
        for (int r = 0; r < 4; ++r) {
            int row = r0 + ty * 4 + r;
            if (row < rows)
#pragma unroll
                for (int c = 0; c < 8; ++c)
                    Qo[(size_t)row * 128 + tx * 8 + c] = acc[r][c] + Bq[tx * 8 + c];
        }
    }
    __syncthreads();

    // ---- panel K (fp16 out) ----
    for (int i = t; i < 64 * 128; i += 256) wsm[i >> 7][i & 127] = Wk[i];
    __syncthreads();
    {
        float acc[4][8] = {};
#pragma unroll 4
        for (int kk = 0; kk < 64; ++kk) {
            float a[4];
#pragma unroll
            for (int r = 0; r < 4; ++r) a[r] = xs[ty * 4 + r][kk];
            float b[8];
#pragma unroll
            for (int c = 0; c < 8; ++c) b[c] = wsm[kk][tx * 8 + c];
#pragma unroll
            for (int r = 0; r < 4; ++r)
#pragma unroll
                for (int c = 0; c < 8; ++c) acc[r][c] = fmaf(a[r], b[c], acc[r][c]);
        }
#pragma unroll
        for (int r = 0; r < 4; ++r) {
            int row = r0 + ty * 4 + r;
            if (row < rows)
#pragma unroll
                for (int c = 0; c < 8; ++c)
                    Ko[(size_t)row * 128 + tx * 8 + c] =
                        __float2half_rn(acc[r][c] + Bk[tx * 8 + c]);
        }
    }
    __syncthreads();

    // ---- panel V (fp16 out) ----
    for (int i = t; i < 64 * 128; i += 256) wsm[i >> 7][i & 127] = Wv[i];
    __syncthreads();
    {
        float acc[4][8] = {};
#pragma unroll 4
        for (int kk = 0; kk < 64; ++kk) {
            float a[4];
#pragma unroll
            for (int r = 0; r < 4; ++r) a[r] = xs[ty * 4 + r][kk];
            float b[8];
#pragma unroll
            for (int c = 0; c < 8; ++c) b[c] = wsm[kk][tx * 8 + c];
#pragma unroll
            for (int r = 0; r < 4; ++r)
#pragma unroll
                for (int c = 0; c < 8; ++c) acc[r][c] = fmaf(a[r], b[c], acc[r][c]);
        }
#pragma unroll
        for (int r = 0; r < 4; ++r) {
            int row = r0 + ty * 4 + r;
            if (row < rows)
#pragma unroll
                for (int c = 0; c < 8; ++c)
                    Vo[(size_t)row * 128 + tx * 8 + c] =
                        __float2half_rn(acc[r][c] + Bv[tx * 8 + c]);
        }
    }
    __syncthreads();

    // ---- panel skip (64 cols, fp32 out) ----
    for (int i = t; i < 64 * 64; i += 256) wsm[i >> 6][i & 63] = Ws[i];
    __syncthreads();
    {
        float acc[4][4] = {};
#pragma unroll 4
        for (int kk = 0; kk < 64; ++kk) {
            float a[4];
#pragma unroll
            for (int r = 0; r < 4; ++r) a[r] = xs[ty * 4 + r][kk];
            float b[4];
#pragma unroll
            for (int c = 0; c < 4; ++c) b[c] = wsm[kk][tx * 4 + c];
#pragma unroll
            for (int r = 0; r < 4; ++r)
#pragma unroll
                for (int c = 0; c < 4; ++c) acc[r][c] = fmaf(a[r], b[c], acc[r][c]);
        }
#pragma unroll
        for (int r = 0; r < 4; ++r) {
            int row = r0 + ty * 4 + r;
            if (row < rows)
#pragma unroll
                for (int c = 0; c < 4; ++c)
                    skipo[(size_t)row * 64 + tx * 4 + c] = acc[r][c] + Bs[tx * 4 + c];
        }
    }
}

// ---------------------------------------------------------------------------
// Attention: one wave per dst node; lanes 0-31 head0, 32-63 head1, 2 ch/lane.
// fp16 K/V gathers, 4-edge batched online softmax.
// ---------------------------------------------------------------------------
__global__ __launch_bounds__(256) void attn_kernel(const float* __restrict__ Q,
                                                   const __half* __restrict__ K,
                                                   const __half* __restrict__ V,
                                                   const int* __restrict__ offs,
                                                   const int* __restrict__ ssrc,
                                                   float* __restrict__ out, int n) {
    int gid  = blockIdx.x * 256 + threadIdx.x;
    int node = gid >> 6;
    int lane = threadIdx.x & 63;
    if (node >= n) return;

    const float2 qv = *(const float2*)(Q + (size_t)node * 128 + lane * 2);
    const int beg = offs[node], end = offs[node + 1];

    const __half2* K2 = (const __half2*)K;
    const __half2* V2 = (const __half2*)V;

    float m = -INFINITY, l = 0.f;
    float2 acc = make_float2(0.f, 0.f);

    int i = beg;
    for (; i + 4 <= end; i += 4) {
        int s0 = ssrc[i], s1 = ssrc[i + 1], s2 = ssrc[i + 2], s3 = ssrc[i + 3];
        __half2 hk0 = K2[(size_t)s0 * 64 + lane];
        __half2 hk1 = K2[(size_t)s1 * 64 + lane];
        __half2 hk2 = K2[(size_t)s2 * 64 + lane];
        __half2 hk3 = K2[(size_t)s3 * 64 + lane];
        __half2 hv0 = V2[(size_t)s0 * 64 + lane];
        __half2 hv1 = V2[(size_t)s1 * 64 + lane];
        __half2 hv2 = V2[(size_t)s2 * 64 + lane];
        __half2 hv3 = V2[(size_t)s3 * 64 + lane];

        float d0 = fmaf(qv.x, __half2float(hk0.x), qv.y * __half2float(hk0.y));
        float d1 = fmaf(qv.x, __half2float(hk1.x), qv.y * __half2float(hk1.y));
        float d2 = fmaf(qv.x, __half2float(hk2.x), qv.y * __half2float(hk2.y));
        float d3 = fmaf(qv.x, __half2float(hk3.x), qv.y * __half2float(hk3.y));

        d0 += __shfl_xor(d0, 1);  d1 += __shfl_xor(d1, 1);
        d2 += __shfl_xor(d2, 1);  d3 += __shfl_xor(d3, 1);
        d0 += __shfl_xor(d0, 2);  d1 += __shfl_xor(d1, 2);
        d2 += __shfl_xor(d2, 2);  d3 += __shfl_xor(d3, 2);
        d0 += __shfl_xor(d0, 4);  d1 += __shfl_xor(d1, 4);
        d2 += __shfl_xor(d2, 4);  d3 += __shfl_xor(d3, 4);
        d0 += __shfl_xor(d0, 8);  d1 += __shfl_xor(d1, 8);
        d2 += __shfl_xor(d2, 8);  d3 += __shfl_xor(d3, 8);
        d0 += __shfl_xor(d0, 16); d1 += __shfl_xor(d1, 16);
        d2 += __shfl_xor(d2, 16); d3 += __shfl_xor(d3, 16);

        float a0 = d0 * 0.125f, a1 = d1 * 0.125f, a2 = d2 * 0.125f, a3 = d3 * 0.125f;
        float mx = fmaxf(fmaxf(fmaxf(a0, a1), fmaxf(a2, a3)), m);
        float scale = __expf(m - mx);
        float p0 = __expf(a0 - mx), p1 = __expf(a1 - mx);
        float p2 = __expf(a2 - mx), p3 = __expf(a3 - mx);

        float ax = acc.x * scale, ay = acc.y * scale;
        ax = fmaf(p0, __half2float(hv0.x), ax);
        ay = fmaf(p0, __half2float(hv0.y), ay);
        ax = fmaf(p1, __half2float(hv1.x), ax);
        ay = fmaf(p1, __half2float(hv1.y), ay);
        ax = fmaf(p2, __half2float(hv2.x), ax);
        ay = fmaf(p2, __half2float(hv2.y), ay);
        ax = fmaf(p3, __half2float(hv3.x), ax);
        ay = fmaf(p3, __half2float(hv3.y), ay);
        acc.x = ax; acc.y = ay;
        l = fmaf(l, scale, p0 + p1 + p2 + p3);
        m = mx;
    }
    for (; i < end; ++i) {
        int s = ssrc[i];
        __half2 hk = K2[(size_t)s * 64 + lane];
        __half2 hv = V2[(size_t)s * 64 + lane];
        float d = fmaf(qv.x, __half2float(hk.x), qv.y * __half2float(hk.y));
        d += __shfl_xor(d, 1);
        d += __shfl_xor(d, 2);
        d += __shfl_xor(d, 4);
        d += __shfl_xor(d, 8);
        d += __shfl_xor(d, 16);
        float a = d * 0.125f;
        float mnew  = fmaxf(m, a);
        float scale = __expf(m - mnew);
        float p     = __expf(a - mnew);
        acc.x = fmaf(p, __half2float(hv.x), acc.x * scale);
        acc.y = fmaf(p, __half2float(hv.y), acc.y * scale);
        l = fmaf(l, scale, p);
        m = mnew;
    }

    float inv = 1.f / (l + 1e-16f);
    float rx = acc.x * inv, ry = acc.y * inv;
    float ox = __shfl_xor(rx, 32);
    float oy = __shfl_xor(ry, 32);
    float mx2 = 0.5f * (rx + ox), my2 = 0.5f * (ry + oy);

    if (lane < 32) {
        float2* o = (float2*)(out + (size_t)node * 64 + lane * 2);
        float2 cur = *o;
        cur.x += mx2;
        cur.y += my2;
        *o = cur;
    }
}

// ---------------------------------------------------------------------------
// Host launch
// ---------------------------------------------------------------------------
extern "C" void kernel_launch(void* const* d_in, const int* in_sizes, int n_in,
                              void* d_out, int out_size, void* d_ws, size_t ws_size,
                              hipStream_t stream) {
    const float* x  = (const float*)d_in[0];
    const int*   ei = (const int*)d_in[1];  // [2,E]: row0=src, row1=dst
    const int N = in_sizes[0] / 64;
    const int E = in_sizes[1] / 2;

    const float* w[16];
    for (int i = 0; i < 16; ++i) w[i] = (const float*)d_in[2 + i];

    char* base = (char*)d_ws;
    size_t off = 0;
    auto alloc = [&](size_t bytes) {
        void* p = base + off;
        off = (off + bytes + 255) & ~(size_t)255;
        return p;
    };
    float*  q    = (float*)alloc((size_t)N * 128 * 4);
    __half* kbuf = (__half*)alloc((size_t)N * 128 * 2);
    __half* v    = (__half*)alloc((size_t)N * 128 * 2);
    float*  h1   = (float*)alloc((size_t)N * 64 * 4);
    int* counts    = (int*)alloc((size_t)N * 4);
    int* offsets   = (int*)alloc((size_t)(N + 1) * 4);
    int* cursor    = (int*)alloc((size_t)N * 4);
    int* ssrc      = (int*)alloc((size_t)E * 4);
    int* partials  = (int*)alloc(1024 * 4);
    int* blockbase = (int*)alloc(1024 * 4);

    // --- CSR build (graph shared by both layers) ---
    hipMemsetAsync(counts, 0, (size_t)N * 4, stream);
    int eb = (E + 255) / 256;
    int nb = (N + 255) / 256;  // 196 <= 256
    hist_kernel<<<eb, 256, 0, stream>>>(ei + E, counts, E);
    partial_kernel<<<nb, 256, 0, stream>>>(counts, partials, N);
    scanp_kernel<<<1, 256, 0, stream>>>(partials, blockbase, nb);
    final_kernel<<<nb, 256, 0, stream>>>(counts, blockbase, offsets, cursor, N, E);
    scatter_kernel<<<eb, 256, 0, stream>>>(ei, ei + E, cursor, ssrc, E);

    const int gb = (N + 63) / 64;
    const int ab = (N * 64 + 255) / 256;

    for (int layer = 0; layer < 2; ++layer) {
        const float* in = layer ? h1 : x;
        float* outp = layer ? (float*)d_out : h1;
        const float* const* W = w + layer * 8;
        gemm_fused<<<gb, 256, 0, stream>>>(in, N, W[0], W[1], W[2], W[3], W[4], W[5],
                                           W[6], W[7], q, kbuf, v, outp);
        attn_kernel<<<ab, 256, 0, stream>>>(q, kbuf, v, offsets, ssrc, outp, N);
    }
}

// Round 4
// 324.459 us; speedup vs baseline: 2.0337x; 1.0803x over previous
//
#include <hip/hip_runtime.h>
#include <hip/hip_fp16.h>
#include <math.h>

// N=50000 nodes, E=800000 edges, D=64, H=2 heads, C=64 per-head, H*C=128
// Output cols concatenated: [Q:128 | K:128 | V:128 | skip:64] = 448

typedef _Float16 half8 __attribute__((ext_vector_type(8)));
typedef float floatx4 __attribute__((ext_vector_type(4)));

// ---------------------------------------------------------------------------
// CSR build kernels
// ---------------------------------------------------------------------------
__global__ __launch_bounds__(256) void hist_kernel(const int* __restrict__ dst,
                                                   int* __restrict__ counts, int e) {
    int i = blockIdx.x * 256 + threadIdx.x;
    if (i < e) atomicAdd(&counts[dst[i]], 1);
}

__global__ __launch_bounds__(256) void partial_kernel(const int* __restrict__ counts,
                                                      int* __restrict__ partials, int n) {
    int idx = blockIdx.x * 256 + threadIdx.x;
    int v = (idx < n) ? counts[idx] : 0;
    for (int off = 1; off < 64; off <<= 1) v += __shfl_xor(v, off);
    __shared__ int ws[4];
    int wid = threadIdx.x >> 6;
    if ((threadIdx.x & 63) == 0) ws[wid] = v;
    __syncthreads();
    if (threadIdx.x == 0) partials[blockIdx.x] = ws[0] + ws[1] + ws[2] + ws[3];
}

__global__ __launch_bounds__(256) void scanp_kernel(const int* __restrict__ partials,
                                                    int* __restrict__ blockbase, int nb) {
    __shared__ int s[256];
    int t = threadIdx.x;
    int v = (t < nb) ? partials[t] : 0;
    s[t] = v;
    __syncthreads();
    for (int off = 1; off < 256; off <<= 1) {
        int u = (t >= off) ? s[t - off] : 0;
        __syncthreads();
        s[t] += u;
        __syncthreads();
    }
    if (t < nb) blockbase[t] = s[t] - v;
}

__global__ __launch_bounds__(256) void final_kernel(const int* __restrict__ counts,
                                                    const int* __restrict__ blockbase,
                                                    int* __restrict__ offsets,
                                                    int* __restrict__ cursor,
                                                    int n, int total) {
    __shared__ int s[256];
    int t = threadIdx.x;
    int idx = blockIdx.x * 256 + t;
    int v = (idx < n) ? counts[idx] : 0;
    s[t] = v;
    __syncthreads();
    for (int off = 1; off < 256; off <<= 1) {
        int u = (t >= off) ? s[t - off] : 0;
        __syncthreads();
        s[t] += u;
        __syncthreads();
    }
    if (idx < n) {
        int ex = blockbase[blockIdx.x] + s[t] - v;
        offsets[idx] = ex;
        cursor[idx]  = ex;
    }
    if (idx == 0) offsets[n] = total;
}

__global__ __launch_bounds__(256) void scatter_kernel(const int* __restrict__ src,
                                                      const int* __restrict__ dst,
                                                      int* __restrict__ cursor,
                                                      int* __restrict__ ssrc, int e) {
    int i = blockIdx.x * 256 + threadIdx.x;
    if (i < e) {
        int pos = atomicAdd(&cursor[dst[i]], 1);
        ssrc[pos] = src[i];
    }
}

// ---------------------------------------------------------------------------
// Precompute: cast X to f16; transpose+cast weights into WhT[448][64], Ball[448]
// ---------------------------------------------------------------------------
__global__ __launch_bounds__(256) void cast_x(const float* __restrict__ x,
                                              _Float16* __restrict__ xh, int n) {
    int i = blockIdx.x * 256 + threadIdx.x;
    int stride = gridDim.x * 256;
    for (; i * 4 + 3 < n; i += stride) {
        float4 f = *(const float4*)(x + i * 4);
        _Float16* o = xh + i * 4;
        o[0] = (_Float16)f.x; o[1] = (_Float16)f.y;
        o[2] = (_Float16)f.z; o[3] = (_Float16)f.w;
    }
}

__global__ __launch_bounds__(256) void prep_w(
    const float* __restrict__ Wq, const float* __restrict__ Bq,
    const float* __restrict__ Wk, const float* __restrict__ Bk,
    const float* __restrict__ Wv, const float* __restrict__ Bv,
    const float* __restrict__ Ws, const float* __restrict__ Bs,
    _Float16* __restrict__ WhT, float* __restrict__ Ball) {
    int idx = blockIdx.x * 256 + threadIdx.x;  // 448*64 = 28672
    if (idx >= 448 * 64) return;
    int c = idx >> 6, k = idx & 63;
    float v;
    if (c < 128)      v = Wq[k * 128 + c];
    else if (c < 256) v = Wk[k * 128 + (c - 128)];
    else if (c < 384) v = Wv[k * 128 + (c - 256)];
    else              v = Ws[k * 64 + (c - 384)];
    WhT[c * 64 + k] = (_Float16)v;
    if (k == 0) {
        float b;
        if (c < 128)      b = Bq[c];
        else if (c < 256) b = Bk[c - 128];
        else if (c < 384) b = Bv[c - 256];
        else              b = Bs[c - 384];
        Ball[c] = b;
    }
}

// ---------------------------------------------------------------------------
// MFMA GEMM: [rows,64]f16 @ WhT^T -> Q fp32 [N,128], K/V f16 [N,128], skip fp32 [N,64]
// 1 wave = 16 rows; 28 col-tiles of 16; no LDS, no barriers.
// ---------------------------------------------------------------------------
__global__ __launch_bounds__(256) void gemm_mfma(
    const _Float16* __restrict__ Xh, int rows,
    const _Float16* __restrict__ WhT,   // [448][64]
    const float* __restrict__ Ball,     // [448]
    float* __restrict__ Qo, __half* __restrict__ Ko, __half* __restrict__ Vo,
    float* __restrict__ So) {
    const int w    = threadIdx.x >> 6;
    const int lane = threadIdx.x & 63;
    const int kg   = lane >> 4;     // k-group 0..3
    const int li   = lane & 15;
    const int rbase = blockIdx.x * 64 + w * 16;

    // A fragments: row = rbase+li, k = kg*8 + j (+32 for step 1)
    int arow = rbase + li;
    int crow = arow < rows ? arow : rows - 1;
    const _Float16* xp = Xh + (size_t)crow * 64 + kg * 8;
    half8 a0 = *(const half8*)xp;
    half8 a1 = *(const half8*)(xp + 32);

    const int orow = rbase + kg * 4;  // D row = orow + r

#pragma unroll
    for (int t = 0; t < 28; ++t) {
        const int col = t * 16 + li;
        const _Float16* wp = WhT + (size_t)col * 64 + kg * 8;
        half8 b0 = *(const half8*)wp;
        half8 b1 = *(const half8*)(wp + 32);
        floatx4 acc = {0.f, 0.f, 0.f, 0.f};
        acc = __builtin_amdgcn_mfma_f32_16x16x32_f16(a0, b0, acc, 0, 0, 0);
        acc = __builtin_amdgcn_mfma_f32_16x16x32_f16(a1, b1, acc, 0, 0, 0);
        const float bias = Ball[col];
#pragma unroll
        for (int r = 0; r < 4; ++r) {
            int ro = orow + r;
            if (ro < rows) {
                float vv = acc[r] + bias;
                if (t < 8)       Qo[(size_t)ro * 128 + col] = vv;
                else if (t < 16) Ko[(size_t)ro * 128 + (col - 128)] = __float2half_rn(vv);
                else if (t < 24) Vo[(size_t)ro * 128 + (col - 256)] = __float2half_rn(vv);
                else             So[(size_t)ro * 64 + (col - 384)] = vv;
            }
        }
    }
}

// ---------------------------------------------------------------------------
// Attention: 1 wave/node; lanes 0-31 head0, 32-63 head1; 2 ch/lane.
// 8-edge batched online softmax, fp16 K/V gathers.
// out = skip + mean_heads(softmax(qk/8) @ v); HALF_OUT -> f16 (layer-1 h1).
// ---------------------------------------------------------------------------
template <int HALF_OUT>
__global__ __launch_bounds__(256) void attn_kernel(
    const float* __restrict__ Q, const __half* __restrict__ K,
    const __half* __restrict__ V, const int* __restrict__ offs,
    const int* __restrict__ ssrc, const float* __restrict__ skip,
    float* __restrict__ outF, _Float16* __restrict__ outH, int n) {
    int node = (blockIdx.x * 256 + threadIdx.x) >> 6;
    int lane = threadIdx.x & 63;
    if (node >= n) return;

    const float2 qv = *(const float2*)(Q + (size_t)node * 128 + lane * 2);
    const int beg = offs[node], end = offs[node + 1];
    const __half2* K2 = (const __half2*)K;
    const __half2* V2 = (const __half2*)V;

    float m = -INFINITY, l = 0.f, ax = 0.f, ay = 0.f;

    int i = beg;
    for (; i + 8 <= end; i += 8) {
        int s[8];
#pragma unroll
        for (int j = 0; j < 8; ++j) s[j] = ssrc[i + j];
        __half2 hk[8], hv[8];
#pragma unroll
        for (int j = 0; j < 8; ++j) hk[j] = K2[(size_t)s[j] * 64 + lane];
#pragma unroll
        for (int j = 0; j < 8; ++j) hv[j] = V2[(size_t)s[j] * 64 + lane];
        float d[8];
#pragma unroll
        for (int j = 0; j < 8; ++j) {
            float2 kf = __half22float2(hk[j]);
            d[j] = fmaf(qv.x, kf.x, qv.y * kf.y);
        }
#pragma unroll
        for (int off = 1; off < 32; off <<= 1) {
#pragma unroll
            for (int j = 0; j < 8; ++j) d[j] += __shfl_xor(d[j], off);
        }
        float mx = m;
#pragma unroll
        for (int j = 0; j < 8; ++j) {
            d[j] *= 0.125f;
            mx = fmaxf(mx, d[j]);
        }
        float scale = __expf(m - mx);
        ax *= scale; ay *= scale; l *= scale;
#pragma unroll
        for (int j = 0; j < 8; ++j) {
            float p = __expf(d[j] - mx);
            float2 vf = __half22float2(hv[j]);
            ax = fmaf(p, vf.x, ax);
            ay = fmaf(p, vf.y, ay);
            l += p;
        }
        m = mx;
    }
    for (; i < end; ++i) {
        int s = ssrc[i];
        __half2 hk = K2[(size_t)s * 64 + lane];
        __half2 hv = V2[(size_t)s * 64 + lane];
        float2 kf = __half22float2(hk);
        float d = fmaf(qv.x, kf.x, qv.y * kf.y);
        d += __shfl_xor(d, 1);
        d += __shfl_xor(d, 2);
        d += __shfl_xor(d, 4);
        d += __shfl_xor(d, 8);
        d += __shfl_xor(d, 16);
        d *= 0.125f;
        float mnew  = fmaxf(m, d);
        float scale = __expf(m - mnew);
        float p     = __expf(d - mnew);
        float2 vf = __half22float2(hv);
        ax = fmaf(p, vf.x, ax * scale);
        ay = fmaf(p, vf.y, ay * scale);
        l = fmaf(l, scale, p);
        m = mnew;
    }

    float inv = 1.f / (l + 1e-16f);
    float rx = ax * inv, ry = ay * inv;
    rx = 0.5f * (rx + __shfl_xor(rx, 32));
    ry = 0.5f * (ry + __shfl_xor(ry, 32));

    if (lane < 32) {
        float2 sk = *(const float2*)(skip + (size_t)node * 64 + lane * 2);
        float ox = sk.x + rx, oy = sk.y + ry;
        if (HALF_OUT) {
            _Float16* o = outH + (size_t)node * 64 + lane * 2;
            o[0] = (_Float16)ox;
            o[1] = (_Float16)oy;
        } else {
            *(float2*)(outF + (size_t)node * 64 + lane * 2) = make_float2(ox, oy);
        }
    }
}

// ---------------------------------------------------------------------------
// Host launch
// ---------------------------------------------------------------------------
extern "C" void kernel_launch(void* const* d_in, const int* in_sizes, int n_in,
                              void* d_out, int out_size, void* d_ws, size_t ws_size,
                              hipStream_t stream) {
    const float* x  = (const float*)d_in[0];
    const int*   ei = (const int*)d_in[1];  // [2,E]: row0=src, row1=dst
    const int N = in_sizes[0] / 64;
    const int E = in_sizes[1] / 2;

    const float* w[16];
    for (int i = 0; i < 16; ++i) w[i] = (const float*)d_in[2 + i];

    char* base = (char*)d_ws;
    size_t off = 0;
    auto alloc = [&](size_t bytes) {
        void* p = base + off;
        off = (off + bytes + 255) & ~(size_t)255;
        return p;
    };
    float*    q    = (float*)alloc((size_t)N * 128 * 4);
    __half*   kbuf = (__half*)alloc((size_t)N * 128 * 2);
    __half*   v    = (__half*)alloc((size_t)N * 128 * 2);
    float*    sk1  = (float*)alloc((size_t)N * 64 * 4);
    _Float16* xh   = (_Float16*)alloc((size_t)N * 64 * 2);
    _Float16* h1h  = (_Float16*)alloc((size_t)N * 64 * 2);
    _Float16* wht1 = (_Float16*)alloc(448 * 64 * 2);
    _Float16* wht2 = (_Float16*)alloc(448 * 64 * 2);
    float*    ball1 = (float*)alloc(448 * 4);
    float*    ball2 = (float*)alloc(448 * 4);
    int* counts    = (int*)alloc((size_t)N * 4);
    int* offsets   = (int*)alloc((size_t)(N + 1) * 4);
    int* cursor    = (int*)alloc((size_t)N * 4);
    int* ssrc      = (int*)alloc((size_t)E * 4);
    int* partials  = (int*)alloc(1024 * 4);
    int* blockbase = (int*)alloc(1024 * 4);

    // --- precompute casts / weight transpose ---
    cast_x<<<2048, 256, 0, stream>>>(x, xh, N * 64);
    prep_w<<<(448 * 64 + 255) / 256, 256, 0, stream>>>(
        w[0], w[1], w[2], w[3], w[4], w[5], w[6], w[7], wht1, ball1);
    prep_w<<<(448 * 64 + 255) / 256, 256, 0, stream>>>(
        w[8], w[9], w[10], w[11], w[12], w[13], w[14], w[15], wht2, ball2);

    // --- CSR build (graph shared by both layers) ---
    hipMemsetAsync(counts, 0, (size_t)N * 4, stream);
    int eb = (E + 255) / 256;
    int nb = (N + 255) / 256;
    hist_kernel<<<eb, 256, 0, stream>>>(ei + E, counts, E);
    partial_kernel<<<nb, 256, 0, stream>>>(counts, partials, N);
    scanp_kernel<<<1, 256, 0, stream>>>(partials, blockbase, nb);
    final_kernel<<<nb, 256, 0, stream>>>(counts, blockbase, offsets, cursor, N, E);
    scatter_kernel<<<eb, 256, 0, stream>>>(ei, ei + E, cursor, ssrc, E);

    const int gb = (N + 63) / 64;
    const int ab = (N * 64 + 255) / 256;

    // --- layer 1 ---
    gemm_mfma<<<gb, 256, 0, stream>>>(xh, N, wht1, ball1, q, kbuf, v, sk1);
    attn_kernel<1><<<ab, 256, 0, stream>>>(q, kbuf, v, offsets, ssrc, sk1,
                                           nullptr, h1h, N);
    // --- layer 2 ---
    gemm_mfma<<<gb, 256, 0, stream>>>(h1h, N, wht2, ball2, q, kbuf, v, (float*)d_out);
    attn_kernel<0><<<ab, 256, 0, stream>>>(q, kbuf, v, offsets, ssrc, (float*)d_out,
                                           (float*)d_out, nullptr, N);
}

// Round 5
// 293.738 us; speedup vs baseline: 2.2464x; 1.1046x over previous
//
#include <hip/hip_runtime.h>
#include <hip/hip_fp16.h>
#include <math.h>

// N=50000 nodes, E=800000 edges, D=64, H=2 heads, C=64 per-head, H*C=128
// GEMM output cols concatenated: [Q:128 | K:128 | V:128 | skip:64] = 448

typedef _Float16 half8 __attribute__((ext_vector_type(8)));
typedef float floatx4 __attribute__((ext_vector_type(4)));

struct __align__(16) H8 { __half2 a, b, c, d; };   // 8 f16 = 16 B
struct __align__(16) F16x8 { _Float16 v[8]; };     // 16 B

// ---------------------------------------------------------------------------
// CSR build kernels
// ---------------------------------------------------------------------------
__global__ __launch_bounds__(256) void hist_kernel(const int* __restrict__ dst,
                                                   int* __restrict__ counts, int e) {
    int i = blockIdx.x * 256 + threadIdx.x;
    if (i < e) atomicAdd(&counts[dst[i]], 1);
}

__global__ __launch_bounds__(256) void partial_kernel(const int* __restrict__ counts,
                                                      int* __restrict__ partials, int n) {
    int idx = blockIdx.x * 256 + threadIdx.x;
    int v = (idx < n) ? counts[idx] : 0;
    for (int off = 1; off < 64; off <<= 1) v += __shfl_xor(v, off);
    __shared__ int ws[4];
    int wid = threadIdx.x >> 6;
    if ((threadIdx.x & 63) == 0) ws[wid] = v;
    __syncthreads();
    if (threadIdx.x == 0) partials[blockIdx.x] = ws[0] + ws[1] + ws[2] + ws[3];
}

__global__ __launch_bounds__(256) void scanp_kernel(const int* __restrict__ partials,
                                                    int* __restrict__ blockbase, int nb) {
    __shared__ int s[256];
    int t = threadIdx.x;
    int v = (t < nb) ? partials[t] : 0;
    s[t] = v;
    __syncthreads();
    for (int off = 1; off < 256; off <<= 1) {
        int u = (t >= off) ? s[t - off] : 0;
        __syncthreads();
        s[t] += u;
        __syncthreads();
    }
    if (t < nb) blockbase[t] = s[t] - v;
}

__global__ __launch_bounds__(256) void final_kernel(const int* __restrict__ counts,
                                                    const int* __restrict__ blockbase,
                                                    int* __restrict__ offsets,
                                                    int* __restrict__ cursor,
                                                    int n, int total) {
    __shared__ int s[256];
    int t = threadIdx.x;
    int idx = blockIdx.x * 256 + t;
    int v = (idx < n) ? counts[idx] : 0;
    s[t] = v;
    __syncthreads();
    for (int off = 1; off < 256; off <<= 1) {
        int u = (t >= off) ? s[t - off] : 0;
        __syncthreads();
        s[t] += u;
        __syncthreads();
    }
    if (idx < n) {
        int ex = blockbase[blockIdx.x] + s[t] - v;
        offsets[idx] = ex;
        cursor[idx]  = ex;
    }
    if (idx == 0) offsets[n] = total;
}

__global__ __launch_bounds__(256) void scatter_kernel(const int* __restrict__ src,
                                                      const int* __restrict__ dst,
                                                      int* __restrict__ cursor,
                                                      int* __restrict__ ssrc, int e) {
    int i = blockIdx.x * 256 + threadIdx.x;
    if (i < e) {
        int pos = atomicAdd(&cursor[dst[i]], 1);
        ssrc[pos] = src[i];
    }
}

// ---------------------------------------------------------------------------
// Precompute: cast X to f16; transpose+cast weights into WhT[448][64], Ball[448]
// ---------------------------------------------------------------------------
__global__ __launch_bounds__(256) void cast_x(const float* __restrict__ x,
                                              _Float16* __restrict__ xh, int n) {
    int i = blockIdx.x * 256 + threadIdx.x;
    int stride = gridDim.x * 256;
    for (; i * 4 + 3 < n; i += stride) {
        float4 f = *(const float4*)(x + i * 4);
        _Float16* o = xh + i * 4;
        o[0] = (_Float16)f.x; o[1] = (_Float16)f.y;
        o[2] = (_Float16)f.z; o[3] = (_Float16)f.w;
    }
}

__global__ __launch_bounds__(256) void prep_w(
    const float* __restrict__ Wq, const float* __restrict__ Bq,
    const float* __restrict__ Wk, const float* __restrict__ Bk,
    const float* __restrict__ Wv, const float* __restrict__ Bv,
    const float* __restrict__ Ws, const float* __restrict__ Bs,
    _Float16* __restrict__ WhT, float* __restrict__ Ball) {
    int idx = blockIdx.x * 256 + threadIdx.x;  // 448*64 = 28672
    if (idx >= 448 * 64) return;
    int c = idx >> 6, k = idx & 63;
    float v;
    if (c < 128)      v = Wq[k * 128 + c];
    else if (c < 256) v = Wk[k * 128 + (c - 128)];
    else if (c < 384) v = Wv[k * 128 + (c - 256)];
    else              v = Ws[k * 64 + (c - 384)];
    WhT[c * 64 + k] = (_Float16)v;
    if (k == 0) {
        float b;
        if (c < 128)      b = Bq[c];
        else if (c < 256) b = Bk[c - 128];
        else if (c < 384) b = Bv[c - 256];
        else              b = Bs[c - 384];
        Ball[c] = b;
    }
}

// ---------------------------------------------------------------------------
// MFMA GEMM: [rows,64]f16 @ WhT^T -> Q f16 [N,128], KV f16 [N,256], skip fp32 [N,64]
// 1 wave = 16 rows; 28 col-tiles of 16; no LDS, no barriers.
// ---------------------------------------------------------------------------
__global__ __launch_bounds__(256) void gemm_mfma(
    const _Float16* __restrict__ Xh, int rows,
    const _Float16* __restrict__ WhT,   // [448][64]
    const float* __restrict__ Ball,     // [448]
    _Float16* __restrict__ Qo,          // [N][128]
    _Float16* __restrict__ KVo,         // [N][256] = [K:128 | V:128]
    float* __restrict__ So) {           // [N][64]
    const int w    = threadIdx.x >> 6;
    const int lane = threadIdx.x & 63;
    const int kg   = lane >> 4;     // k-group 0..3
    const int li   = lane & 15;
    const int rbase = blockIdx.x * 64 + w * 16;

    int arow = rbase + li;
    int crow = arow < rows ? arow : rows - 1;
    const _Float16* xp = Xh + (size_t)crow * 64 + kg * 8;
    half8 a0 = *(const half8*)xp;
    half8 a1 = *(const half8*)(xp + 32);

    const int orow = rbase + kg * 4;  // D row = orow + r

#pragma unroll
    for (int t = 0; t < 28; ++t) {
        const int col = t * 16 + li;
        const _Float16* wp = WhT + (size_t)col * 64 + kg * 8;
        half8 b0 = *(const half8*)wp;
        half8 b1 = *(const half8*)(wp + 32);
        floatx4 acc = {0.f, 0.f, 0.f, 0.f};
        acc = __builtin_amdgcn_mfma_f32_16x16x32_f16(a0, b0, acc, 0, 0, 0);
        acc = __builtin_amdgcn_mfma_f32_16x16x32_f16(a1, b1, acc, 0, 0, 0);
        const float bias = Ball[col];
#pragma unroll
        for (int r = 0; r < 4; ++r) {
            int ro = orow + r;
            if (ro < rows) {
                float vv = acc[r] + bias;
                if (t < 8)       Qo[(size_t)ro * 128 + col] = (_Float16)vv;
                else if (t < 16) KVo[(size_t)ro * 256 + (col - 128)] = (_Float16)vv;
                else if (t < 24) KVo[(size_t)ro * 256 + 128 + (col - 256)] = (_Float16)vv;
                else             So[(size_t)ro * 64 + (col - 384)] = vv;
            }
        }
    }
}

// ---------------------------------------------------------------------------
// Attention: 1 wave/node. lane = slot(2b) | head(1b) | li(3b): 8 ch/lane,
// 4 edge-slots, 2 edges/slot/iter (8 edges/iter). Per-slot online softmax,
// slot states merged at end, then per-head normalize + head mean.
// ---------------------------------------------------------------------------
template <int HALF_OUT>
__global__ __launch_bounds__(256) void attn_kernel(
    const _Float16* __restrict__ Qh,    // [N][128] f16
    const _Float16* __restrict__ KV,    // [N][256] f16
    const int* __restrict__ offs, const int* __restrict__ ssrc,
    const float* __restrict__ skip,     // [N][64] f32
    float* __restrict__ outF, _Float16* __restrict__ outH, int n) {
    int node = (blockIdx.x * 256 + threadIdx.x) >> 6;
    int lane = threadIdx.x & 63;
    if (node >= n) return;
    const int slot = lane >> 4;
    const int koff = ((lane >> 3) & 1) * 64 + (lane & 7) * 8;  // head*64 + li*8

    H8 q = *(const H8*)(Qh + (size_t)node * 128 + koff);

    const int beg = offs[node], end = offs[node + 1];
    float m = -INFINITY, l = 0.f;
    float acc[8];
#pragma unroll
    for (int j = 0; j < 8; ++j) acc[j] = 0.f;

    int i = beg;
    for (; i + 8 <= end; i += 8) {
        int s0 = ssrc[i + slot], s1 = ssrc[i + 4 + slot];
        const _Float16* p0 = KV + (size_t)s0 * 256 + koff;
        const _Float16* p1 = KV + (size_t)s1 * 256 + koff;
        H8 k0 = *(const H8*)p0;
        H8 k1 = *(const H8*)p1;
        H8 v0 = *(const H8*)(p0 + 128);
        H8 v1 = *(const H8*)(p1 + 128);

        __half2 dh0 = __hfma2(q.a, k0.a, __hfma2(q.b, k0.b, __hfma2(q.c, k0.c, __hmul2(q.d, k0.d))));
        __half2 dh1 = __hfma2(q.a, k1.a, __hfma2(q.b, k1.b, __hfma2(q.c, k1.c, __hmul2(q.d, k1.d))));
        float2 f0 = __half22float2(dh0), f1 = __half22float2(dh1);
        float d0 = f0.x + f0.y, d1 = f1.x + f1.y;
        d0 += __shfl_xor(d0, 1); d1 += __shfl_xor(d1, 1);
        d0 += __shfl_xor(d0, 2); d1 += __shfl_xor(d1, 2);
        d0 += __shfl_xor(d0, 4); d1 += __shfl_xor(d1, 4);
        d0 *= 0.125f; d1 *= 0.125f;

        float mx = fmaxf(fmaxf(d0, d1), m);
        float sc = __expf(m - mx);          // mx finite here
        float p0e = __expf(d0 - mx), p1e = __expf(d1 - mx);
        l = fmaf(l, sc, p0e + p1e);

        float2 va[4] = {__half22float2(v0.a), __half22float2(v0.b),
                        __half22float2(v0.c), __half22float2(v0.d)};
        float2 vb[4] = {__half22float2(v1.a), __half22float2(v1.b),
                        __half22float2(v1.c), __half22float2(v1.d)};
#pragma unroll
        for (int j = 0; j < 4; ++j) {
            acc[2*j]   = fmaf(p1e, vb[j].x, fmaf(p0e, va[j].x, acc[2*j]   * sc));
            acc[2*j+1] = fmaf(p1e, vb[j].y, fmaf(p0e, va[j].y, acc[2*j+1] * sc));
        }
        m = mx;
    }
    if (i < end) {  // predicated tail, 1..7 edges
        int e0 = i + slot, e1 = i + 4 + slot;
        bool b0 = e0 < end, b1 = e1 < end;
        int s0 = ssrc[b0 ? e0 : end - 1];
        int s1 = ssrc[b1 ? e1 : end - 1];
        const _Float16* p0 = KV + (size_t)s0 * 256 + koff;
        const _Float16* p1 = KV + (size_t)s1 * 256 + koff;
        H8 k0 = *(const H8*)p0;
        H8 k1 = *(const H8*)p1;
        H8 v0 = *(const H8*)(p0 + 128);
        H8 v1 = *(const H8*)(p1 + 128);

        __half2 dh0 = __hfma2(q.a, k0.a, __hfma2(q.b, k0.b, __hfma2(q.c, k0.c, __hmul2(q.d, k0.d))));
        __half2 dh1 = __hfma2(q.a, k1.a, __hfma2(q.b, k1.b, __hfma2(q.c, k1.c, __hmul2(q.d, k1.d))));
        float2 f0 = __half22float2(dh0), f1 = __half22float2(dh1);
        float d0 = f0.x + f0.y, d1 = f1.x + f1.y;
        d0 += __shfl_xor(d0, 1); d1 += __shfl_xor(d1, 1);
        d0 += __shfl_xor(d0, 2); d1 += __shfl_xor(d1, 2);
        d0 += __shfl_xor(d0, 4); d1 += __shfl_xor(d1, 4);
        d0 = b0 ? d0 * 0.125f : -INFINITY;
        d1 = b1 ? d1 * 0.125f : -INFINITY;

        float mx = fmaxf(fmaxf(d0, d1), m);
        float sc = (m == -INFINITY) ? 0.f : __expf(m - mx);
        float p0e = b0 ? __expf(d0 - mx) : 0.f;
        float p1e = b1 ? __expf(d1 - mx) : 0.f;
        l = fmaf(l, sc, p0e + p1e);

        float2 va[4] = {__half22float2(v0.a), __half22float2(v0.b),
                        __half22float2(v0.c), __half22float2(v0.d)};
        float2 vb[4] = {__half22float2(v1.a), __half22float2(v1.b),
                        __half22float2(v1.c), __half22float2(v1.d)};
#pragma unroll
        for (int j = 0; j < 4; ++j) {
            acc[2*j]   = fmaf(p1e, vb[j].x, fmaf(p0e, va[j].x, acc[2*j]   * sc));
            acc[2*j+1] = fmaf(p1e, vb[j].y, fmaf(p0e, va[j].y, acc[2*j+1] * sc));
        }
        m = mx;
    }

    // merge the 4 slot states (xor 16, xor 32)
#pragma unroll
    for (int off = 16; off <= 32; off <<= 1) {
        float mo = __shfl_xor(m, off);
        float lo = __shfl_xor(l, off);
        float ao[8];
#pragma unroll
        for (int j = 0; j < 8; ++j) ao[j] = __shfl_xor(acc[j], off);
        float mm = fmaxf(m, mo);
        float sa = (m  == -INFINITY) ? 0.f : __expf(m  - mm);
        float sb = (mo == -INFINITY) ? 0.f : __expf(mo - mm);
        l = l * sa + lo * sb;
#pragma unroll
        for (int j = 0; j < 8; ++j) acc[j] = acc[j] * sa + ao[j] * sb;
        m = mm;
    }
    // per-head normalize, then head mean (xor 8)
    float inv = 1.f / (l + 1e-16f);
    float r[8];
#pragma unroll
    for (int j = 0; j < 8; ++j) r[j] = acc[j] * inv;
#pragma unroll
    for (int j = 0; j < 8; ++j) r[j] = 0.5f * (r[j] + __shfl_xor(r[j], 8));

    if (lane < 8) {  // slot0, head0: lane owns ch lane*8..+7
        const float4* sp = (const float4*)(skip + (size_t)node * 64 + lane * 8);
        float4 s0 = sp[0], s1 = sp[1];
        float o[8] = {s0.x + r[0], s0.y + r[1], s0.z + r[2], s0.w + r[3],
                      s1.x + r[4], s1.y + r[5], s1.z + r[6], s1.w + r[7]};
        if (HALF_OUT) {
            F16x8 h;
#pragma unroll
            for (int j = 0; j < 8; ++j) h.v[j] = (_Float16)o[j];
            *(F16x8*)(outH + (size_t)node * 64 + lane * 8) = h;
        } else {
            float4* op = (float4*)(outF + (size_t)node * 64 + lane * 8);
            op[0] = make_float4(o[0], o[1], o[2], o[3]);
            op[1] = make_float4(o[4], o[5], o[6], o[7]);
        }
    }
}

// ---------------------------------------------------------------------------
// Host launch
// ---------------------------------------------------------------------------
extern "C" void kernel_launch(void* const* d_in, const int* in_sizes, int n_in,
                              void* d_out, int out_size, void* d_ws, size_t ws_size,
                              hipStream_t stream) {
    const float* x  = (const float*)d_in[0];
    const int*   ei = (const int*)d_in[1];  // [2,E]: row0=src, row1=dst
    const int N = in_sizes[0] / 64;
    const int E = in_sizes[1] / 2;

    const float* w[16];
    for (int i = 0; i < 16; ++i) w[i] = (const float*)d_in[2 + i];

    char* base = (char*)d_ws;
    size_t off = 0;
    auto alloc = [&](size_t bytes) {
        void* p = base + off;
        off = (off + bytes + 255) & ~(size_t)255;
        return p;
    };
    _Float16* qh   = (_Float16*)alloc((size_t)N * 128 * 2);
    _Float16* kv   = (_Float16*)alloc((size_t)N * 256 * 2);
    float*    sk1  = (float*)alloc((size_t)N * 64 * 4);
    _Float16* xh   = (_Float16*)alloc((size_t)N * 64 * 2);
    _Float16* h1h  = (_Float16*)alloc((size_t)N * 64 * 2);
    _Float16* wht1 = (_Float16*)alloc(448 * 64 * 2);
    _Float16* wht2 = (_Float16*)alloc(448 * 64 * 2);
    float*    ball1 = (float*)alloc(448 * 4);
    float*    ball2 = (float*)alloc(448 * 4);
    int* counts    = (int*)alloc((size_t)N * 4);
    int* offsets   = (int*)alloc((size_t)(N + 1) * 4);
    int* cursor    = (int*)alloc((size_t)N * 4);
    int* ssrc      = (int*)alloc((size_t)E * 4);
    int* partials  = (int*)alloc(1024 * 4);
    int* blockbase = (int*)alloc(1024 * 4);

    // --- precompute casts / weight transpose ---
    cast_x<<<2048, 256, 0, stream>>>(x, xh, N * 64);
    prep_w<<<(448 * 64 + 255) / 256, 256, 0, stream>>>(
        w[0], w[1], w[2], w[3], w[4], w[5], w[6], w[7], wht1, ball1);
    prep_w<<<(448 * 64 + 255) / 256, 256, 0, stream>>>(
        w[8], w[9], w[10], w[11], w[12], w[13], w[14], w[15], wht2, ball2);

    // --- CSR build (graph shared by both layers) ---
    hipMemsetAsync(counts, 0, (size_t)N * 4, stream);
    int eb = (E + 255) / 256;
    int nb = (N + 255) / 256;
    hist_kernel<<<eb, 256, 0, stream>>>(ei + E, counts, E);
    partial_kernel<<<nb, 256, 0, stream>>>(counts, partials, N);
    scanp_kernel<<<1, 256, 0, stream>>>(partials, blockbase, nb);
    final_kernel<<<nb, 256, 0, stream>>>(counts, blockbase, offsets, cursor, N, E);
    scatter_kernel<<<eb, 256, 0, stream>>>(ei, ei + E, cursor, ssrc, E);

    const int gb = (N + 63) / 64;
    const int ab = (N * 64 + 255) / 256;

    // --- layer 1 ---
    gemm_mfma<<<gb, 256, 0, stream>>>(xh, N, wht1, ball1, qh, kv, sk1);
    attn_kernel<1><<<ab, 256, 0, stream>>>(qh, kv, offsets, ssrc, sk1,
                                           nullptr, h1h, N);
    // --- layer 2 ---
    gemm_mfma<<<gb, 256, 0, stream>>>(h1h, N, wht2, ball2, qh, kv, (float*)d_out);
    attn_kernel<0><<<ab, 256, 0, stream>>>(qh, kv, offsets, ssrc, (float*)d_out,
                                           (float*)d_out, nullptr, N);
}

// Round 6
// 291.182 us; speedup vs baseline: 2.2661x; 1.0088x over previous
//
#include <hip/hip_runtime.h>
#include <hip/hip_fp16.h>
#include <math.h>

// N=50000 nodes, E=800000 edges, D=64, H=2 heads, C=64 per-head, H*C=128
// GEMM output cols concatenated: [Q:128 | K:128 | V:128 | skip:64] = 448

typedef _Float16 half8 __attribute__((ext_vector_type(8)));
typedef _Float16 half4 __attribute__((ext_vector_type(4)));
typedef float floatx4 __attribute__((ext_vector_type(4)));

struct __align__(16) H8 { __half2 a, b, c, d; };   // 8 f16 = 16 B
struct __align__(16) F16x8 { _Float16 v[8]; };     // 16 B

static __device__ inline __half2 shfl_xor_h2(__half2 v, int off) {
    union { __half2 h; int i; } u;
    u.h = v;
    u.i = __shfl_xor(u.i, off);
    return u.h;
}

// ---------------------------------------------------------------------------
// CSR build kernels
// ---------------------------------------------------------------------------
__global__ __launch_bounds__(256) void hist_kernel(const int* __restrict__ dst,
                                                   int* __restrict__ counts, int e) {
    int i = blockIdx.x * 256 + threadIdx.x;
    if (i < e) atomicAdd(&counts[dst[i]], 1);
}

__global__ __launch_bounds__(256) void partial_kernel(const int* __restrict__ counts,
                                                      int* __restrict__ partials, int n) {
    int idx = blockIdx.x * 256 + threadIdx.x;
    int v = (idx < n) ? counts[idx] : 0;
    for (int off = 1; off < 64; off <<= 1) v += __shfl_xor(v, off);
    __shared__ int ws[4];
    int wid = threadIdx.x >> 6;
    if ((threadIdx.x & 63) == 0) ws[wid] = v;
    __syncthreads();
    if (threadIdx.x == 0) partials[blockIdx.x] = ws[0] + ws[1] + ws[2] + ws[3];
}

__global__ __launch_bounds__(256) void scanp_kernel(const int* __restrict__ partials,
                                                    int* __restrict__ blockbase, int nb) {
    __shared__ int s[256];
    int t = threadIdx.x;
    int v = (t < nb) ? partials[t] : 0;
    s[t] = v;
    __syncthreads();
    for (int off = 1; off < 256; off <<= 1) {
        int u = (t >= off) ? s[t - off] : 0;
        __syncthreads();
        s[t] += u;
        __syncthreads();
    }
    if (t < nb) blockbase[t] = s[t] - v;
}

__global__ __launch_bounds__(256) void final_kernel(const int* __restrict__ counts,
                                                    const int* __restrict__ blockbase,
                                                    int* __restrict__ offsets,
                                                    int* __restrict__ cursor,
                                                    int n, int total) {
    __shared__ int s[256];
    int t = threadIdx.x;
    int idx = blockIdx.x * 256 + t;
    int v = (idx < n) ? counts[idx] : 0;
    s[t] = v;
    __syncthreads();
    for (int off = 1; off < 256; off <<= 1) {
        int u = (t >= off) ? s[t - off] : 0;
        __syncthreads();
        s[t] += u;
        __syncthreads();
    }
    if (idx < n) {
        int ex = blockbase[blockIdx.x] + s[t] - v;
        offsets[idx] = ex;
        cursor[idx]  = ex;
    }
    if (idx == 0) offsets[n] = total;
}

__global__ __launch_bounds__(256) void scatter_kernel(const int* __restrict__ src,
                                                      const int* __restrict__ dst,
                                                      int* __restrict__ cursor,
                                                      int* __restrict__ ssrc, int e) {
    int i = blockIdx.x * 256 + threadIdx.x;
    if (i < e) {
        int pos = atomicAdd(&cursor[dst[i]], 1);
        ssrc[pos] = src[i];
    }
}

// ---------------------------------------------------------------------------
// Weight prep: transpose+cast into WhT[448][64] f16, Ball[448] f32
// ---------------------------------------------------------------------------
__global__ __launch_bounds__(256) void prep_w(
    const float* __restrict__ Wq, const float* __restrict__ Bq,
    const float* __restrict__ Wk, const float* __restrict__ Bk,
    const float* __restrict__ Wv, const float* __restrict__ Bv,
    const float* __restrict__ Ws, const float* __restrict__ Bs,
    _Float16* __restrict__ WhT, float* __restrict__ Ball) {
    int idx = blockIdx.x * 256 + threadIdx.x;  // 448*64 = 28672
    if (idx >= 448 * 64) return;
    int c = idx >> 6, k = idx & 63;
    float v;
    if (c < 128)      v = Wq[k * 128 + c];
    else if (c < 256) v = Wk[k * 128 + (c - 128)];
    else if (c < 384) v = Wv[k * 128 + (c - 256)];
    else              v = Ws[k * 64 + (c - 384)];
    WhT[c * 64 + k] = (_Float16)v;
    if (k == 0) {
        float b;
        if (c < 128)      b = Bq[c];
        else if (c < 256) b = Bk[c - 128];
        else if (c < 384) b = Bv[c - 256];
        else              b = Bs[c - 384];
        Ball[c] = b;
    }
}

// ---------------------------------------------------------------------------
// MFMA GEMM (operand-swapped): [rows,64] @ WhT^T -> Q f16, KV f16, skip f32.
// mfma(A=w_frag, B=x_frag): D row = w-col (4*kg+reg), D col = x-row (li)
// => each lane owns 4 CONSECUTIVE out-cols of ONE node row -> packed 8B stores.
// F32IN: input is fp32 (layer 1, fused cast); else f16.
// ---------------------------------------------------------------------------
template <int F32IN>
__global__ __launch_bounds__(256) void gemm_mfma(
    const void* __restrict__ Xin, int rows,
    const _Float16* __restrict__ WhT,   // [448][64]
    const float* __restrict__ Ball,     // [448]
    _Float16* __restrict__ Qo,          // [N][128]
    _Float16* __restrict__ KVo,         // [N][256] = [K:128 | V:128]
    float* __restrict__ So) {           // [N][64]
    const int lane = threadIdx.x & 63;
    const int w    = threadIdx.x >> 6;
    const int kg   = lane >> 4;
    const int li   = lane & 15;
    const int rbase = blockIdx.x * 64 + w * 16;
    const int row  = rbase + li;
    const int crow = row < rows ? row : rows - 1;

    half8 a0, a1;
    if constexpr (F32IN) {
        const float* xp = (const float*)Xin + (size_t)crow * 64 + kg * 8;
        float4 f0 = *(const float4*)xp;
        float4 f1 = *(const float4*)(xp + 4);
        float4 f2 = *(const float4*)(xp + 32);
        float4 f3 = *(const float4*)(xp + 36);
        a0 = half8{(_Float16)f0.x, (_Float16)f0.y, (_Float16)f0.z, (_Float16)f0.w,
                   (_Float16)f1.x, (_Float16)f1.y, (_Float16)f1.z, (_Float16)f1.w};
        a1 = half8{(_Float16)f2.x, (_Float16)f2.y, (_Float16)f2.z, (_Float16)f2.w,
                   (_Float16)f3.x, (_Float16)f3.y, (_Float16)f3.z, (_Float16)f3.w};
    } else {
        const _Float16* xp = (const _Float16*)Xin + (size_t)crow * 64 + kg * 8;
        a0 = *(const half8*)xp;
        a1 = *(const half8*)(xp + 32);
    }

#pragma unroll
    for (int t = 0; t < 28; ++t) {
        const _Float16* wp = WhT + (size_t)(t * 16 + li) * 64 + kg * 8;
        half8 b0 = *(const half8*)wp;
        half8 b1 = *(const half8*)(wp + 32);
        floatx4 acc = {0.f, 0.f, 0.f, 0.f};
        acc = __builtin_amdgcn_mfma_f32_16x16x32_f16(b0, a0, acc, 0, 0, 0);
        acc = __builtin_amdgcn_mfma_f32_16x16x32_f16(b1, a1, acc, 0, 0, 0);
        const int c0 = t * 16 + kg * 4;
        float4 bias = *(const float4*)(Ball + c0);
        if (row < rows) {
            float o0 = acc[0] + bias.x, o1 = acc[1] + bias.y;
            float o2 = acc[2] + bias.z, o3 = acc[3] + bias.w;
            if (t < 8) {
                *(half4*)(Qo + (size_t)row * 128 + c0) =
                    half4{(_Float16)o0, (_Float16)o1, (_Float16)o2, (_Float16)o3};
            } else if (t < 24) {
                *(half4*)(KVo + (size_t)row * 256 + (c0 - 128)) =
                    half4{(_Float16)o0, (_Float16)o1, (_Float16)o2, (_Float16)o3};
            } else {
                *(float4*)(So + (size_t)row * 64 + (c0 - 384)) =
                    make_float4(o0, o1, o2, o3);
            }
        }
    }
}

// ---------------------------------------------------------------------------
// Attention: 1 wave/node. lane = slot(2b) | head(1b) | li(3b): 8 ch/lane,
// 4 edge-slots, 2 edges/slot/iter (8 edges/iter). f16 packed V-accumulate,
// packed half2 dot reduce. Slot states merged at end, head mean, +skip.
// ---------------------------------------------------------------------------
template <int HALF_OUT>
__global__ __launch_bounds__(256) void attn_kernel(
    const _Float16* __restrict__ Qh,    // [N][128] f16
    const _Float16* __restrict__ KV,    // [N][256] f16
    const int* __restrict__ offs, const int* __restrict__ ssrc,
    const float* __restrict__ skip,     // [N][64] f32
    float* __restrict__ outF, _Float16* __restrict__ outH, int n) {
    int node = (blockIdx.x * 256 + threadIdx.x) >> 6;
    int lane = threadIdx.x & 63;
    if (node >= n) return;
    const int slot = lane >> 4;
    const int koff = ((lane >> 3) & 1) * 64 + (lane & 7) * 8;  // head*64 + li*8

    H8 q = *(const H8*)(Qh + (size_t)node * 128 + koff);

    const int beg = offs[node], end = offs[node + 1];
    float m = -INFINITY, l = 0.f;
    __half2 hz = __float2half2_rn(0.f);
    __half2 ha = hz, hb = hz, hc = hz, hd = hz;   // packed O accumulator (8 ch)

    int i = beg;
    for (; i + 8 <= end; i += 8) {
        int s0 = ssrc[i + slot], s1 = ssrc[i + 4 + slot];
        const _Float16* p0 = KV + (size_t)s0 * 256 + koff;
        const _Float16* p1 = KV + (size_t)s1 * 256 + koff;
        H8 k0 = *(const H8*)p0;
        H8 k1 = *(const H8*)p1;
        H8 v0 = *(const H8*)(p0 + 128);
        H8 v1 = *(const H8*)(p1 + 128);

        __half2 dh0 = __hfma2(q.a, k0.a, __hfma2(q.b, k0.b, __hfma2(q.c, k0.c, __hmul2(q.d, k0.d))));
        __half2 dh1 = __hfma2(q.a, k1.a, __hfma2(q.b, k1.b, __hfma2(q.c, k1.c, __hmul2(q.d, k1.d))));
        __half2 pd = __halves2half2(__hadd(dh0.x, dh0.y), __hadd(dh1.x, dh1.y));
        pd = __hadd2(pd, shfl_xor_h2(pd, 1));
        pd = __hadd2(pd, shfl_xor_h2(pd, 2));
        pd = __hadd2(pd, shfl_xor_h2(pd, 4));
        float d0 = __half2float(pd.x) * 0.125f;
        float d1 = __half2float(pd.y) * 0.125f;

        float mx = fmaxf(fmaxf(d0, d1), m);
        float sc = __expf(m - mx);
        float p0e = __expf(d0 - mx), p1e = __expf(d1 - mx);
        l = fmaf(l, sc, p0e + p1e);

        __half2 hsc = __float2half2_rn(sc);
        __half2 hp0 = __float2half2_rn(p0e);
        __half2 hp1 = __float2half2_rn(p1e);
        ha = __hfma2(hp0, v0.a, __hfma2(hp1, v1.a, __hmul2(ha, hsc)));
        hb = __hfma2(hp0, v0.b, __hfma2(hp1, v1.b, __hmul2(hb, hsc)));
        hc = __hfma2(hp0, v0.c, __hfma2(hp1, v1.c, __hmul2(hc, hsc)));
        hd = __hfma2(hp0, v0.d, __hfma2(hp1, v1.d, __hmul2(hd, hsc)));
        m = mx;
    }
    if (i < end) {  // predicated tail, 1..7 edges
        int e0 = i + slot, e1 = i + 4 + slot;
        bool b0 = e0 < end, b1 = e1 < end;
        int s0 = ssrc[b0 ? e0 : end - 1];
        int s1 = ssrc[b1 ? e1 : end - 1];
        const _Float16* p0 = KV + (size_t)s0 * 256 + koff;
        const _Float16* p1 = KV + (size_t)s1 * 256 + koff;
        H8 k0 = *(const H8*)p0;
        H8 k1 = *(const H8*)p1;
        H8 v0 = *(const H8*)(p0 + 128);
        H8 v1 = *(const H8*)(p1 + 128);

        __half2 dh0 = __hfma2(q.a, k0.a, __hfma2(q.b, k0.b, __hfma2(q.c, k0.c, __hmul2(q.d, k0.d))));
        __half2 dh1 = __hfma2(q.a, k1.a, __hfma2(q.b, k1.b, __hfma2(q.c, k1.c, __hmul2(q.d, k1.d))));
        __half2 pd = __halves2half2(__hadd(dh0.x, dh0.y), __hadd(dh1.x, dh1.y));
        pd = __hadd2(pd, shfl_xor_h2(pd, 1));
        pd = __hadd2(pd, shfl_xor_h2(pd, 2));
        pd = __hadd2(pd, shfl_xor_h2(pd, 4));
        float d0 = b0 ? __half2float(pd.x) * 0.125f : -INFINITY;
        float d1 = b1 ? __half2float(pd.y) * 0.125f : -INFINITY;

        float mx = fmaxf(fmaxf(d0, d1), m);
        float sc = (m == -INFINITY) ? 0.f : __expf(m - mx);
        float p0e = b0 ? __expf(d0 - mx) : 0.f;
        float p1e = b1 ? __expf(d1 - mx) : 0.f;
        l = fmaf(l, sc, p0e + p1e);

        __half2 hsc = __float2half2_rn(sc);
        __half2 hp0 = __float2half2_rn(p0e);
        __half2 hp1 = __float2half2_rn(p1e);
        ha = __hfma2(hp0, v0.a, __hfma2(hp1, v1.a, __hmul2(ha, hsc)));
        hb = __hfma2(hp0, v0.b, __hfma2(hp1, v1.b, __hmul2(hb, hsc)));
        hc = __hfma2(hp0, v0.c, __hfma2(hp1, v1.c, __hmul2(hc, hsc)));
        hd = __hfma2(hp0, v0.d, __hfma2(hp1, v1.d, __hmul2(hd, hsc)));
        m = mx;
    }

    // unpack accumulator to f32 for the slot merges
    float acc[8];
    {
        float2 t0 = __half22float2(ha), t1 = __half22float2(hb);
        float2 t2 = __half22float2(hc), t3 = __half22float2(hd);
        acc[0] = t0.x; acc[1] = t0.y; acc[2] = t1.x; acc[3] = t1.y;
        acc[4] = t2.x; acc[5] = t2.y; acc[6] = t3.x; acc[7] = t3.y;
    }

    // merge the 4 slot states (xor 16, xor 32)
#pragma unroll
    for (int off = 16; off <= 32; off <<= 1) {
        float mo = __shfl_xor(m, off);
        float lo = __shfl_xor(l, off);
        float ao[8];
#pragma unroll
        for (int j = 0; j < 8; ++j) ao[j] = __shfl_xor(acc[j], off);
        float mm = fmaxf(m, mo);
        float sa = (m  == -INFINITY) ? 0.f : __expf(m  - mm);
        float sb = (mo == -INFINITY) ? 0.f : __expf(mo - mm);
        l = l * sa + lo * sb;
#pragma unroll
        for (int j = 0; j < 8; ++j) acc[j] = acc[j] * sa + ao[j] * sb;
        m = mm;
    }
    // per-head normalize, then head mean (xor 8)
    float inv = 1.f / (l + 1e-16f);
    float r[8];
#pragma unroll
    for (int j = 0; j < 8; ++j) r[j] = acc[j] * inv;
#pragma unroll
    for (int j = 0; j < 8; ++j) r[j] = 0.5f * (r[j] + __shfl_xor(r[j], 8));

    if (lane < 8) {  // slot0, head0: lane owns ch lane*8..+7
        const float4* sp = (const float4*)(skip + (size_t)node * 64 + lane * 8);
        float4 s0 = sp[0], s1 = sp[1];
        float o[8] = {s0.x + r[0], s0.y + r[1], s0.z + r[2], s0.w + r[3],
                      s1.x + r[4], s1.y + r[5], s1.z + r[6], s1.w + r[7]};
        if (HALF_OUT) {
            F16x8 h;
#pragma unroll
            for (int j = 0; j < 8; ++j) h.v[j] = (_Float16)o[j];
            *(F16x8*)(outH + (size_t)node * 64 + lane * 8) = h;
        } else {
            float4* op = (float4*)(outF + (size_t)node * 64 + lane * 8);
            op[0] = make_float4(o[0], o[1], o[2], o[3]);
            op[1] = make_float4(o[4], o[5], o[6], o[7]);
        }
    }
}

// ---------------------------------------------------------------------------
// Host launch
// ---------------------------------------------------------------------------
extern "C" void kernel_launch(void* const* d_in, const int* in_sizes, int n_in,
                              void* d_out, int out_size, void* d_ws, size_t ws_size,
                              hipStream_t stream) {
    const float* x  = (const float*)d_in[0];
    const int*   ei = (const int*)d_in[1];  // [2,E]: row0=src, row1=dst
    const int N = in_sizes[0] / 64;
    const int E = in_sizes[1] / 2;

    const float* w[16];
    for (int i = 0; i < 16; ++i) w[i] = (const float*)d_in[2 + i];

    char* base = (char*)d_ws;
    size_t off = 0;
    auto alloc = [&](size_t bytes) {
        void* p = base + off;
        off = (off + bytes + 255) & ~(size_t)255;
        return p;
    };
    _Float16* qh   = (_Float16*)alloc((size_t)N * 128 * 2);
    _Float16* kv   = (_Float16*)alloc((size_t)N * 256 * 2);
    float*    sk1  = (float*)alloc((size_t)N * 64 * 4);
    _Float16* h1h  = (_Float16*)alloc((size_t)N * 64 * 2);
    _Float16* wht1 = (_Float16*)alloc(448 * 64 * 2);
    _Float16* wht2 = (_Float16*)alloc(448 * 64 * 2);
    float*    ball1 = (float*)alloc(448 * 4);
    float*    ball2 = (float*)alloc(448 * 4);
    int* counts    = (int*)alloc((size_t)N * 4);
    int* offsets   = (int*)alloc((size_t)(N + 1) * 4);
    int* cursor    = (int*)alloc((size_t)N * 4);
    int* ssrc      = (int*)alloc((size_t)E * 4);
    int* partials  = (int*)alloc(1024 * 4);
    int* blockbase = (int*)alloc(1024 * 4);

    // --- weight prep ---
    prep_w<<<(448 * 64 + 255) / 256, 256, 0, stream>>>(
        w[0], w[1], w[2], w[3], w[4], w[5], w[6], w[7], wht1, ball1);
    prep_w<<<(448 * 64 + 255) / 256, 256, 0, stream>>>(
        w[8], w[9], w[10], w[11], w[12], w[13], w[14], w[15], wht2, ball2);

    // --- CSR build (graph shared by both layers) ---
    hipMemsetAsync(counts, 0, (size_t)N * 4, stream);
    int eb = (E + 255) / 256;
    int nb = (N + 255) / 256;
    hist_kernel<<<eb, 256, 0, stream>>>(ei + E, counts, E);
    partial_kernel<<<nb, 256, 0, stream>>>(counts, partials, N);
    scanp_kernel<<<1, 256, 0, stream>>>(partials, blockbase, nb);
    final_kernel<<<nb, 256, 0, stream>>>(counts, blockbase, offsets, cursor, N, E);
    scatter_kernel<<<eb, 256, 0, stream>>>(ei, ei + E, cursor, ssrc, E);

    const int gb = (N + 63) / 64;
    const int ab = (N * 64 + 255) / 256;

    // --- layer 1 (fused fp32->f16 cast of X) ---
    gemm_mfma<1><<<gb, 256, 0, stream>>>(x, N, wht1, ball1, qh, kv, sk1);
    attn_kernel<1><<<ab, 256, 0, stream>>>(qh, kv, offsets, ssrc, sk1,
                                           nullptr, h1h, N);
    // --- layer 2 ---
    gemm_mfma<0><<<gb, 256, 0, stream>>>(h1h, N, wht2, ball2, qh, kv, (float*)d_out);
    attn_kernel<0><<<ab, 256, 0, stream>>>(qh, kv, offsets, ssrc, (float*)d_out,
                                           (float*)d_out, nullptr, N);
}